// Round 1
// baseline (3197.702 us; speedup 1.0000x reference)
//
#include <hip/hip_runtime.h>

// NodeGCN: GCNConv + 2x GINConv (edge-attr MLPs) + BN + concat + 2-layer head.
// Round 1: all-f32, fused per-edge MLP+gather+scatter kernel, LDS-tiled GEMMs.
// ws layout: [deg (256KB pad)][hbuf 19.2MB][tmp/agg 19.2MB][feats 57.6MB] ~= 96.3MB

#define HH 96
#define EDGEF 16
#define CAT (3 * HH)

// ---------------- generic tiled GEMM: C[M,F] = act(A[M,K] @ W[K,F] + b) ----------
template <int F, bool RELU>
__global__ __launch_bounds__(256) void gemm_kernel(
    const float* __restrict__ A, int lda,
    const float* __restrict__ W,
    const float* __restrict__ bias,
    float* __restrict__ C, int ldc,
    int M, int K)
{
    constexpr int BM = 64, BK = 32;
    constexpr int FPT = F / 16;           // 6 for F=96, 4 for F=64
    __shared__ float As[BM][BK + 1];
    __shared__ float Ws[BK][F];

    const int tid = threadIdx.x;
    const int ty = tid >> 4, tx = tid & 15;
    const int m0 = blockIdx.x * BM;

    float acc[4][FPT];
#pragma unroll
    for (int i = 0; i < 4; ++i)
#pragma unroll
        for (int j = 0; j < FPT; ++j) acc[i][j] = 0.f;

    for (int k0 = 0; k0 < K; k0 += BK) {
        __syncthreads();
#pragma unroll
        for (int i = 0; i < (BM * BK) / 256; ++i) {
            int idx = i * 256 + tid;
            int r = idx >> 5, c = idx & 31;
            int gr = m0 + r;
            As[r][c] = (gr < M) ? A[(long)gr * lda + k0 + c] : 0.f;
        }
#pragma unroll
        for (int i = 0; i < (BK * F) / 256; ++i) {
            int idx = i * 256 + tid;
            int k = idx / F, f = idx % F;
            Ws[k][f] = W[(long)(k0 + k) * F + f];
        }
        __syncthreads();
#pragma unroll
        for (int k = 0; k < BK; ++k) {
            float a[4], w[FPT];
#pragma unroll
            for (int i = 0; i < 4; ++i) a[i] = As[ty + i * 16][k];
#pragma unroll
            for (int j = 0; j < FPT; ++j) w[j] = Ws[k][tx + j * 16];
#pragma unroll
            for (int i = 0; i < 4; ++i)
#pragma unroll
                for (int j = 0; j < FPT; ++j)
                    acc[i][j] = fmaf(a[i], w[j], acc[i][j]);
        }
    }

#pragma unroll
    for (int i = 0; i < 4; ++i) {
        int r = m0 + ty + i * 16;
        if (r < M) {
#pragma unroll
            for (int j = 0; j < FPT; ++j) {
                int f = tx + j * 16;
                float v = acc[i][j] + bias[f];
                if (RELU) v = fmaxf(v, 0.f);
                C[(long)r * ldc + f] = v;
            }
        }
    }
}

// ---------------- fused edge kernel ---------------------------------------------
// per edge: ee = relu(ea@bw1+bb1)@bw2+bb2 ; msg = [nrm*]relu(h[row]+ee) ;
// atomicAdd(agg[col], msg)
template <bool GCN>
__global__ __launch_bounds__(256) void edge_kernel(
    const float* __restrict__ edge_attr,
    const int* __restrict__ row, const int* __restrict__ col,
    const float* __restrict__ bw1, const float* __restrict__ bb1,
    const float* __restrict__ bw2, const float* __restrict__ bb2,
    const float* __restrict__ h, int h_stride,
    const float* __restrict__ deg,
    float* __restrict__ agg,
    int E)
{
    __shared__ float s_bw1[EDGEF][HH];   // 6 KB
    __shared__ float s_bw2[HH][HH];      // 36 KB
    __shared__ float s_ea[64][EDGEF];    // 4 KB
    __shared__ float s_t[64][100];       // 25.6 KB (pad 96->100 breaks bank alias)
    __shared__ int s_row[64];
    __shared__ int s_col[64];
    __shared__ float s_nrm[64];

    const int tid = threadIdx.x;
    const int ty = tid >> 4, tx = tid & 15;

    for (int idx = tid; idx < EDGEF * HH; idx += 256) s_bw1[idx / HH][idx % HH] = bw1[idx];
    for (int idx = tid; idx < HH * HH; idx += 256) s_bw2[idx / HH][idx % HH] = bw2[idx];

    const int ntiles = (E + 63) >> 6;
    for (int tile = blockIdx.x; tile < ntiles; tile += gridDim.x) {
        const int e0 = tile << 6;
        __syncthreads();   // protect LDS from previous iteration readers
        // stage edge_attr tile
#pragma unroll
        for (int i = 0; i < 4; ++i) {
            int idx = i * 256 + tid;
            int e = idx >> 4, k = idx & 15;
            int ge = e0 + e;
            s_ea[e][k] = (ge < E) ? edge_attr[(long)ge * EDGEF + k] : 0.f;
        }
        if (tid < 64) {
            int ge = e0 + tid;
            if (ge < E) {
                int r = row[ge], c = col[ge];
                s_row[tid] = r; s_col[tid] = c;
                s_nrm[tid] = GCN ? rsqrtf(deg[r]) * rsqrtf(deg[c]) : 1.f;
            } else {
                s_row[tid] = 0; s_col[tid] = 0; s_nrm[tid] = 0.f;
            }
        }
        __syncthreads();

        // t = relu(ea @ bw1 + bb1)  (64 x 96 tile)
#pragma unroll
        for (int i = 0; i < 4; ++i) {
            int e = ty + i * 16;
#pragma unroll
            for (int j = 0; j < 6; ++j) {
                int f = tx + j * 16;
                float acc = bb1[f];
#pragma unroll
                for (int k = 0; k < EDGEF; ++k)
                    acc = fmaf(s_ea[e][k], s_bw1[k][f], acc);
                s_t[e][f] = fmaxf(acc, 0.f);
            }
        }
        __syncthreads();

        // ee = t @ bw2 + bb2, then gather/message/scatter
        float acc[4][6];
#pragma unroll
        for (int i = 0; i < 4; ++i)
#pragma unroll
            for (int j = 0; j < 6; ++j) acc[i][j] = 0.f;

#pragma unroll 4
        for (int k = 0; k < HH; ++k) {
            float a[4], w[6];
#pragma unroll
            for (int i = 0; i < 4; ++i) a[i] = s_t[ty + i * 16][k];
#pragma unroll
            for (int j = 0; j < 6; ++j) w[j] = s_bw2[k][tx + j * 16];
#pragma unroll
            for (int i = 0; i < 4; ++i)
#pragma unroll
                for (int j = 0; j < 6; ++j)
                    acc[i][j] = fmaf(a[i], w[j], acc[i][j]);
        }

#pragma unroll
        for (int i = 0; i < 4; ++i) {
            int e = ty + i * 16;
            if (e0 + e >= E) continue;
            int r = s_row[e];
            int c = s_col[e];
            float nrm = s_nrm[e];
#pragma unroll
            for (int j = 0; j < 6; ++j) {
                int f = tx + j * 16;
                float ee = acc[i][j] + bb2[f];
                float m = fmaxf(h[(long)r * h_stride + f] + ee, 0.f);
                if (GCN) m *= nrm;
                atomicAdd(&agg[c * HH + f], m);
            }
        }
    }
}

// ---------------- small elementwise kernels --------------------------------------
__global__ void deg_init_kernel(float* __restrict__ deg, int N)
{
    int i = blockIdx.x * blockDim.x + threadIdx.x;
    if (i < N) deg[i] = 1.f;
}

__global__ void deg_accum_kernel(const int* __restrict__ row, float* __restrict__ deg, int E)
{
    int e = blockIdx.x * blockDim.x + threadIdx.x;
    if (e < E) atomicAdd(&deg[row[e]], 1.f);
}

__global__ void gcn_epilogue_kernel(
    const float* __restrict__ agg, const float* __restrict__ hbuf,
    const float* __restrict__ root, const float* __restrict__ deg,
    const float* __restrict__ gamma, const float* __restrict__ beta,
    const float* __restrict__ mean, const float* __restrict__ var,
    float* __restrict__ feats, int N)
{
    int idx = blockIdx.x * blockDim.x + threadIdx.x;
    if (idx >= N * HH) return;
    int n = idx / HH, f = idx - n * HH;
    float self = fmaxf(hbuf[idx] + root[f], 0.f) / deg[n];
    float v = fmaxf(agg[idx] + self, 0.f);
    v = (v - mean[f]) * rsqrtf(var[f] + 1e-5f) * gamma[f] + beta[f];
    feats[(long)n * CAT + f] = v;
}

__global__ void gin_pre_kernel(
    const float* __restrict__ h, int h_stride,      // feats slice
    const float* __restrict__ agg,
    const float* __restrict__ eps_arr, int li,
    float* __restrict__ z, int N)
{
    int idx = blockIdx.x * blockDim.x + threadIdx.x;
    if (idx >= N * HH) return;
    int n = idx / HH, f = idx - n * HH;
    z[idx] = (1.f + eps_arr[li]) * h[(long)n * h_stride + f] + agg[idx];
}

__global__ void gin_post_kernel(
    const float* __restrict__ zout,
    const float* __restrict__ gamma, const float* __restrict__ beta,
    const float* __restrict__ mean, const float* __restrict__ var,
    float* __restrict__ feats, int slot, int N)
{
    int idx = blockIdx.x * blockDim.x + threadIdx.x;
    if (idx >= N * HH) return;
    int n = idx / HH, f = idx - n * HH;
    float v = fmaxf(zout[idx], 0.f);
    v = (v - mean[f]) * rsqrtf(var[f] + 1e-5f) * gamma[f] + beta[f];
    feats[(long)n * CAT + slot * HH + f] = v;
}

// ---------------- launch ----------------------------------------------------------
extern "C" void kernel_launch(void* const* d_in, const int* in_sizes, int n_in,
                              void* d_out, int out_size, void* d_ws, size_t ws_size,
                              hipStream_t stream)
{
    const float* x         = (const float*)d_in[0];
    const int*   eidx      = (const int*)d_in[1];
    const float* edge_attr = (const float*)d_in[2];
    const float* gcn_lin_w = (const float*)d_in[3];
    const float* gcn_lin_b = (const float*)d_in[4];
    const float* gcn_root  = (const float*)d_in[5];
    const float* gcn_bw1   = (const float*)d_in[6];
    const float* gcn_bb1   = (const float*)d_in[7];
    const float* gcn_bw2   = (const float*)d_in[8];
    const float* gcn_bb2   = (const float*)d_in[9];
    const float* gin_bw1   = (const float*)d_in[10];
    const float* gin_bb1   = (const float*)d_in[11];
    const float* gin_bw2   = (const float*)d_in[12];
    const float* gin_bb2   = (const float*)d_in[13];
    const float* gin_mw1   = (const float*)d_in[14];
    const float* gin_mb1   = (const float*)d_in[15];
    const float* gin_mw2   = (const float*)d_in[16];
    const float* gin_mb2   = (const float*)d_in[17];
    const float* gin_eps   = (const float*)d_in[18];
    const float* bn_gamma  = (const float*)d_in[19];
    const float* bn_beta   = (const float*)d_in[20];
    const float* bn_mean   = (const float*)d_in[21];
    const float* bn_var    = (const float*)d_in[22];
    const float* fc1_w     = (const float*)d_in[23];
    const float* fc1_b     = (const float*)d_in[24];
    const float* fc2_w     = (const float*)d_in[25];
    const float* fc2_b     = (const float*)d_in[26];
    float* out = (float*)d_out;

    const int N = in_sizes[0] / 128;   // 50000
    const int E = in_sizes[1] / 2;     // 800000
    const int* row = eidx;
    const int* col = eidx + E;

    char* ws = (char*)d_ws;
    float* deg   = (float*)ws;                               // N floats (256KB slot)
    float* hbuf  = (float*)(ws + (size_t)256 * 1024);        // N*96
    float* tmp   = hbuf + (size_t)N * HH;                    // N*96 (agg / mlp temp)
    float* feats = tmp + (size_t)N * HH;                     // N*288
    float* agg = tmp;

    const size_t nh_bytes = (size_t)N * HH * sizeof(float);
    const int ew_blocks = 2048;
    const int nh_grid = (N * HH + 255) / 256;
    const int gemm_grid = (N + 63) / 64;

    // degrees (deg = 1 + outdeg(row)); exact integer counts in f32
    deg_init_kernel<<<(N + 255) / 256, 256, 0, stream>>>(deg, N);
    deg_accum_kernel<<<(E + 255) / 256, 256, 0, stream>>>(row, deg, E);

    // ---- layer 0: GCN ----
    gemm_kernel<HH, false><<<gemm_grid, 256, 0, stream>>>(x, 128, gcn_lin_w, gcn_lin_b,
                                                          hbuf, HH, N, 128);
    hipMemsetAsync(agg, 0, nh_bytes, stream);
    edge_kernel<true><<<ew_blocks, 256, 0, stream>>>(edge_attr, row, col,
                                                     gcn_bw1, gcn_bb1, gcn_bw2, gcn_bb2,
                                                     hbuf, HH, deg, agg, E);
    gcn_epilogue_kernel<<<nh_grid, 256, 0, stream>>>(agg, hbuf, gcn_root, deg,
                                                     bn_gamma, bn_beta, bn_mean, bn_var,
                                                     feats, N);

    // ---- layers 1..2: GIN ----
    for (int i = 0; i < 2; ++i) {
        const float* h_prev = feats + i * HH;   // stride CAT
        hipMemsetAsync(agg, 0, nh_bytes, stream);
        edge_kernel<false><<<ew_blocks, 256, 0, stream>>>(
            edge_attr, row, col,
            gin_bw1 + (size_t)i * EDGEF * HH, gin_bb1 + i * HH,
            gin_bw2 + (size_t)i * HH * HH, gin_bb2 + i * HH,
            h_prev, CAT, deg, agg, E);
        // z = (1+eps)*h + agg  -> hbuf
        gin_pre_kernel<<<nh_grid, 256, 0, stream>>>(h_prev, CAT, agg, gin_eps, i, hbuf, N);
        // z = relu(z@mw1+mb1)@mw2+mb2   (tmp aliases agg; agg is dead now)
        gemm_kernel<HH, true><<<gemm_grid, 256, 0, stream>>>(
            hbuf, HH, gin_mw1 + (size_t)i * HH * HH, gin_mb1 + i * HH, tmp, HH, N, HH);
        gemm_kernel<HH, false><<<gemm_grid, 256, 0, stream>>>(
            tmp, HH, gin_mw2 + (size_t)i * HH * HH, gin_mb2 + i * HH, hbuf, HH, N, HH);
        gin_post_kernel<<<nh_grid, 256, 0, stream>>>(
            hbuf, bn_gamma + (i + 1) * HH, bn_beta + (i + 1) * HH,
            bn_mean + (i + 1) * HH, bn_var + (i + 1) * HH, feats, i + 1, N);
    }

    // ---- head ----
    gemm_kernel<HH, true><<<gemm_grid, 256, 0, stream>>>(feats, CAT, fc1_w, fc1_b,
                                                         hbuf, HH, N, CAT);
    gemm_kernel<64, false><<<gemm_grid, 256, 0, stream>>>(hbuf, HH, fc2_w, fc2_b,
                                                          out, 64, N, HH);
}